// Round 3
// baseline (1600.917 us; speedup 1.0000x reference)
//
#include <hip/hip_runtime.h>
#include <hip/hip_bf16.h>

// RetinaNet head on MI355X: implicit-GEMM bf16 MFMA convs over padded-NHWC
// activations. R3: 4-deep LDS pipeline with counted vmcnt (T3+T4), raw
// s_barrier, setprio around MFMA (T5). Staging via global_load_lds(16B),
// XOR slot-swizzle on source+read (LDS dest linear).

typedef float  f32x4 __attribute__((ext_vector_type(4)));
typedef int    i32x4 __attribute__((ext_vector_type(4)));
typedef __bf16 bfrag __attribute__((ext_vector_type(8)));
typedef __bf16 bf4   __attribute__((ext_vector_type(4)));

struct LevelD {
  int H, W, logW, logHW, P, HW, act_off, aoff, ntn, blk_start, pos_start;
};
struct Desc  { LevelD lv[6]; };
struct FPtrs { const float* f[6]; };

#define ACT_ELEMS  24735744
#define WREG_OFF   0
#define WCLS_OFF   2359296
#define WREGO_OFF  4718592
#define WCLSO_OFF  4773888
#define ACT0_OFF   4898304
#define ACT1_OFF   29634048
#define WS_ELEMS   54369792ull
#define TOTAL_ANCH 65520
#define CLS_BASE   2096640

__device__ __forceinline__ void glds16(const __bf16* g, __bf16* l) {
  __builtin_amdgcn_global_load_lds(
      (const __attribute__((address_space(1))) void*)g,
      (__attribute__((address_space(3))) void*)l, 16, 0, 0);
}

// ---- weight prep: [CO][256ci][3][3] f32 -> [CO][t=9][256ci] bf16 ----
__global__ __launch_bounds__(256) void prep_k(const float* __restrict__ w,
                                              __bf16* __restrict__ o, int total)
{
  for (int i = blockIdx.x * 256 + threadIdx.x; i < total; i += gridDim.x * 256) {
    int co = i / 2304;
    int r  = i - co * 2304;
    int t  = r >> 8;
    int ci = r & 255;
    o[i] = (__bf16)w[((co << 8) + ci) * 9 + t];
  }
}

// ---- NCHW f32 feat -> padded NHWC bf16 (interior only; halos pre-zeroed) ----
__global__ __launch_bounds__(256) void convert_k(FPtrs fp, __bf16* __restrict__ act, Desc d)
{
  __shared__ __bf16 T[16 * 264];
  int b  = blockIdx.x;
  int p0 = b << 4;
  int li = 0;
  #pragma unroll
  for (int i = 1; i < 6; ++i) li = (p0 >= d.lv[i].pos_start) ? i : li;
  LevelD L = d.lv[li];
  int lp  = b * 16 - L.pos_start;
  int tid = threadIdx.x;
  int pl = tid & 15;
  int p  = lp + pl;
  int n  = p >> L.logHW;
  int y  = (p >> L.logW) & (L.H - 1);
  int x  = p & (L.W - 1);
  const float* src = fp.f[li];
  size_t base = (size_t)n * ((size_t)L.HW << 8) + (size_t)y * L.W + x;
  int c0 = tid >> 4;
  #pragma unroll
  for (int it = 0; it < 16; ++it) {
    int c = c0 + (it << 4);
    T[pl * 264 + c] = (__bf16)src[base + (size_t)c * L.HW];
  }
  __syncthreads();
  int p2 = tid >> 4;
  int cc = (tid & 15) << 4;
  int pg = lp + p2;
  int n2 = pg >> L.logHW;
  int y2 = (pg >> L.logW) & (L.H - 1);
  int x2 = pg & (L.W - 1);
  __bf16* dst = act + L.act_off +
      ((size_t)((n2 * (L.H + 2) + y2 + 1) * (L.W + 2) + x2 + 1) << 8) + cc;
  i32x4 v0 = *(const i32x4*)&T[p2 * 264 + cc];
  i32x4 v1 = *(const i32x4*)&T[p2 * 264 + cc + 8];
  *(i32x4*)dst       = v0;
  *(i32x4*)(dst + 8) = v1;
}

// ---- mid conv: 256->256, +bias, ReLU ----
// 128x128 tile, BK=32, 4 waves (2x2). 4-deep LDS ring, counted vmcnt.
__global__ __launch_bounds__(256)
void conv_mid_k(const __bf16* __restrict__ inb, __bf16* __restrict__ outb,
                const __bf16* __restrict__ wT, const float* __restrict__ bias,
                Desc d)
{
  __shared__ __bf16 Al[4][128 * 32];   // linear [co][ci32], 64B rows
  __shared__ __bf16 Bl[4][128 * 32];   // linear [pos][ci32]
  int b  = blockIdx.x;
  int li = 0;
  #pragma unroll
  for (int i = 1; i < 6; ++i) li = (b >= d.lv[i].blk_start) ? i : li;
  LevelD L  = d.lv[li];
  int local = b - L.blk_start;
  int mt = local & 1;
  int nt = local >> 1;
  int m0 = mt << 7;
  int p0 = nt << 7;
  int tid  = threadIdx.x;
  int lane = tid & 63;
  int wv   = tid >> 6;
  int wm = wv >> 1, wn = wv & 1;
  int fr = lane & 15, fg = lane >> 4;
  int Wp = L.W + 2;

  // staging decode: wave wv covers rows wv*16 + r*64 (r=0,1), lane -> (rsub, slot)
  int rsub = lane >> 2;
  int slot = lane & 3;
  int sw   = slot ^ ((rsub >> 1) & 3);          // XOR slot-swizzle (source side)

  const __bf16* gA[2];
  const __bf16* gB[2];
  int ldsA[2];
  #pragma unroll
  for (int r = 0; r < 2; ++r) {
    int row = (r << 6) + (wv << 4) + rsub;
    gA[r] = wT + (m0 + row) * 2304 + (sw << 3);
    int p  = p0 + row;
    int pc = (p < L.P) ? p : 0;
    int n  = pc >> L.logHW;
    int y  = (pc >> L.logW) & (L.H - 1);
    int x  = pc & (L.W - 1);
    gB[r] = inb + L.act_off + (((n * (L.H + 2) + y) * Wp + x) << 8) + (sw << 3);
    ldsA[r] = ((r << 6) + (wv << 4)) << 5;      // row*32 elems, wave base
  }

  // fragment read offsets (swizzled column)
  int csw = ((fg ^ ((fr >> 1) & 3)) << 3);
  int offA[4], offB[4];
  #pragma unroll
  for (int f = 0; f < 4; ++f) {
    offA[f] = (((wm << 6) + (f << 4) + fr) << 5) + csw;
    offB[f] = (((wn << 6) + (f << 4) + fr) << 5) + csw;
  }

  auto stage = [&](int k, int bb) {
    int t  = k >> 3;
    int c0 = (k & 7) << 5;
    int ky = (t >= 6) ? 2 : (t >= 3 ? 1 : 0);
    int kx = t - ky * 3;
    int koffA = (t << 8) + c0;
    int koffB = ((ky * Wp + kx) << 8) + c0;
    glds16(gA[0] + koffA, &Al[bb][ldsA[0]]);
    glds16(gA[1] + koffA, &Al[bb][ldsA[1]]);
    glds16(gB[0] + koffB, &Bl[bb][ldsA[0]]);
    glds16(gB[1] + koffB, &Bl[bb][ldsA[1]]);
  };

  f32x4 acc[4][4] = {};

  auto compute = [&](int cur) {
    bfrag af[4], bfv[4];
    #pragma unroll
    for (int mf = 0; mf < 4; ++mf) af[mf]  = *(const bfrag*)&Al[cur][offA[mf]];
    #pragma unroll
    for (int nf = 0; nf < 4; ++nf) bfv[nf] = *(const bfrag*)&Bl[cur][offB[nf]];
    __builtin_amdgcn_s_setprio(1);
    #pragma unroll
    for (int mf = 0; mf < 4; ++mf)
      #pragma unroll
      for (int nf = 0; nf < 4; ++nf)
        acc[mf][nf] = __builtin_amdgcn_mfma_f32_16x16x32_bf16(af[mf], bfv[nf],
                                                              acc[mf][nf], 0, 0, 0);
    __builtin_amdgcn_s_setprio(0);
  };

  stage(0, 0);
  stage(1, 1);
  stage(2, 2);

  #pragma unroll 1
  for (int k = 0; k < 69; ++k) {
    asm volatile("s_waitcnt vmcnt(8)" ::: "memory");   // stage(k) landed (own)
    __builtin_amdgcn_s_barrier();                      // all waves' stage(k) landed
    __builtin_amdgcn_sched_barrier(0);
    stage(k + 3, (k + 3) & 3);                         // WAR-safe after barrier
    compute(k & 3);
  }
  // tail: k = 69, 70, 71 (no more staging; drain 8 -> 4 -> 0)
  asm volatile("s_waitcnt vmcnt(8)" ::: "memory");
  __builtin_amdgcn_s_barrier();
  __builtin_amdgcn_sched_barrier(0);
  compute(69 & 3);
  asm volatile("s_waitcnt vmcnt(4)" ::: "memory");
  __builtin_amdgcn_s_barrier();
  __builtin_amdgcn_sched_barrier(0);
  compute(70 & 3);
  asm volatile("s_waitcnt vmcnt(0)" ::: "memory");
  __builtin_amdgcn_s_barrier();
  __builtin_amdgcn_sched_barrier(0);
  compute(71 & 3);

  // epilogue: bias + relu -> bf16 NHWC interior
  #pragma unroll
  for (int nf = 0; nf < 4; ++nf) {
    int pp = p0 + (wn << 6) + (nf << 4) + fr;
    if (pp >= L.P) continue;
    int n2 = pp >> L.logHW;
    int y2 = (pp >> L.logW) & (L.H - 1);
    int x2 = pp & (L.W - 1);
    __bf16* ob = outb + L.act_off + (((n2 * (L.H + 2) + y2 + 1) * Wp + x2 + 1) << 8);
    #pragma unroll
    for (int mf = 0; mf < 4; ++mf) {
      int cob = m0 + (wm << 6) + (mf << 4) + (fg << 2);
      f32x4 bb = *(const f32x4*)(bias + cob);
      f32x4 v  = acc[mf][nf];
      bf4 ov;
      #pragma unroll
      for (int j = 0; j < 4; ++j) ov[j] = (__bf16)fmaxf(v[j] + bb[j], 0.0f);
      *(bf4*)(ob + cob) = ov;
    }
  }
}

// ---- out conv: 256->Cout (24 reg / 54 cls), +bias, scatter f32 to d_out ----
__global__ __launch_bounds__(256)
void conv_out_k(const __bf16* __restrict__ inb, const __bf16* __restrict__ wT,
                const float* __restrict__ biasO, float* __restrict__ dout,
                Desc d, int Cout, int isCls)
{
  __shared__ __bf16 Al[4][128 * 32];
  __shared__ __bf16 Bl[4][128 * 32];
  int b  = blockIdx.x;
  int li = 0;
  #pragma unroll
  for (int i = 1; i < 6; ++i) li = (b >= d.lv[i].blk_start) ? i : li;
  LevelD L = d.lv[li];
  int nt = b - L.blk_start;
  int p0 = nt << 7;
  int tid  = threadIdx.x;
  int lane = tid & 63;
  int wv   = tid >> 6;
  int wm = wv >> 1, wn = wv & 1;
  int fr = lane & 15, fg = lane >> 4;
  int Wp = L.W + 2;

  int rsub = lane >> 2;
  int slot = lane & 3;
  int sw   = slot ^ ((rsub >> 1) & 3);

  const __bf16* gA[2];
  const __bf16* gB[2];
  int ldsA[2];
  #pragma unroll
  for (int r = 0; r < 2; ++r) {
    int row = (r << 6) + (wv << 4) + rsub;
    int co  = (row < Cout) ? row : 0;           // clamp dead rows to valid mem
    gA[r] = wT + co * 2304 + (sw << 3);
    int p  = p0 + row;
    int pc = (p < L.P) ? p : 0;
    int n  = pc >> L.logHW;
    int y  = (pc >> L.logW) & (L.H - 1);
    int x  = pc & (L.W - 1);
    gB[r] = inb + L.act_off + (((n * (L.H + 2) + y) * Wp + x) << 8) + (sw << 3);
    ldsA[r] = ((r << 6) + (wv << 4)) << 5;
  }

  int csw = ((fg ^ ((fr >> 1) & 3)) << 3);
  int offA[4], offB[4];
  #pragma unroll
  for (int f = 0; f < 4; ++f) {
    offA[f] = (((wm << 6) + (f << 4) + fr) << 5) + csw;
    offB[f] = (((wn << 6) + (f << 4) + fr) << 5) + csw;
  }

  int mfN = (Cout - (wm << 6) + 15) >> 4;
  mfN = mfN < 0 ? 0 : (mfN > 4 ? 4 : mfN);

  auto stage = [&](int k, int bb) {
    int t  = k >> 3;
    int c0 = (k & 7) << 5;
    int ky = (t >= 6) ? 2 : (t >= 3 ? 1 : 0);
    int kx = t - ky * 3;
    int koffA = (t << 8) + c0;
    int koffB = ((ky * Wp + kx) << 8) + c0;
    glds16(gA[0] + koffA, &Al[bb][ldsA[0]]);
    glds16(gA[1] + koffA, &Al[bb][ldsA[1]]);
    glds16(gB[0] + koffB, &Bl[bb][ldsA[0]]);
    glds16(gB[1] + koffB, &Bl[bb][ldsA[1]]);
  };

  f32x4 acc[4][4] = {};

  auto compute = [&](int cur) {
    bfrag bfv[4];
    #pragma unroll
    for (int nf = 0; nf < 4; ++nf) bfv[nf] = *(const bfrag*)&Bl[cur][offB[nf]];
    __builtin_amdgcn_s_setprio(1);
    #pragma unroll
    for (int mf = 0; mf < 4; ++mf) {
      if (mf < mfN) {
        bfrag af = *(const bfrag*)&Al[cur][offA[mf]];
        #pragma unroll
        for (int nf = 0; nf < 4; ++nf)
          acc[mf][nf] = __builtin_amdgcn_mfma_f32_16x16x32_bf16(af, bfv[nf],
                                                                acc[mf][nf], 0, 0, 0);
      }
    }
    __builtin_amdgcn_s_setprio(0);
  };

  stage(0, 0);
  stage(1, 1);
  stage(2, 2);

  #pragma unroll 1
  for (int k = 0; k < 69; ++k) {
    asm volatile("s_waitcnt vmcnt(8)" ::: "memory");
    __builtin_amdgcn_s_barrier();
    __builtin_amdgcn_sched_barrier(0);
    stage(k + 3, (k + 3) & 3);
    compute(k & 3);
  }
  asm volatile("s_waitcnt vmcnt(8)" ::: "memory");
  __builtin_amdgcn_s_barrier();
  __builtin_amdgcn_sched_barrier(0);
  compute(69 & 3);
  asm volatile("s_waitcnt vmcnt(4)" ::: "memory");
  __builtin_amdgcn_s_barrier();
  __builtin_amdgcn_sched_barrier(0);
  compute(70 & 3);
  asm volatile("s_waitcnt vmcnt(0)" ::: "memory");
  __builtin_amdgcn_s_barrier();
  __builtin_amdgcn_sched_barrier(0);
  compute(71 & 3);

  #pragma unroll
  for (int nf = 0; nf < 4; ++nf) {
    int pp = p0 + (wn << 6) + (nf << 4) + fr;
    if (pp >= L.P) continue;
    int n2 = pp >> L.logHW;
    int y2 = (pp >> L.logW) & (L.H - 1);
    int x2 = pp & (L.W - 1);
    int sp_off = L.aoff + y2 * L.W + x2;
    #pragma unroll
    for (int mf = 0; mf < 4; ++mf) {
      if (mf < mfN) {
        #pragma unroll
        for (int j = 0; j < 4; ++j) {
          int co = (wm << 6) + (mf << 4) + (fg << 2) + j;
          if (co < Cout) {
            float val = acc[mf][nf][j] + biasO[co];
            int g   = co / 6;
            int box = co - g * 6;
            size_t idx;
            if (isCls) idx = (size_t)CLS_BASE + ((size_t)n2 * 9 + g) * TOTAL_ANCH
                             + sp_off + box * L.HW;
            else       idx = ((size_t)n2 * 4 + g) * TOTAL_ANCH + sp_off + box * L.HW;
            dout[idx] = val;
          }
        }
      }
    }
  }
}

extern "C" void kernel_launch(void* const* d_in, const int* in_sizes, int n_in,
                              void* d_out, int out_size, void* d_ws, size_t ws_size,
                              hipStream_t stream) {
  if (ws_size < WS_ELEMS * 2) return;  // fail loud: output stays poisoned

  static const int kH[6]      = {32, 16, 8, 4, 2, 1};
  static const int kW[6]      = {256, 128, 64, 32, 16, 8};
  static const int kLogW[6]   = {8, 7, 6, 5, 4, 3};
  static const int kLogHW[6]  = {13, 11, 9, 7, 5, 3};
  static const int kActOff[6] = {0, 17965056, 22757376, 24109056, 24526848, 24674304};
  static const int kAoff[6]   = {0, 49152, 61440, 64512, 65280, 65472};
  static const int kNtn[6]    = {512, 128, 32, 8, 2, 1};
  static const int kBlkMid[6] = {0, 1024, 1280, 1344, 1360, 1364};
  static const int kBlkOut[6] = {0, 512, 640, 672, 680, 682};
  static const int kPosSt[6]  = {0, 65536, 81920, 86016, 87040, 87296};

  FPtrs fp;
  for (int i = 0; i < 6; ++i) fp.f[i] = (const float*)d_in[i];
  const float* reg_w  = (const float*)d_in[6];
  const float* reg_b  = (const float*)d_in[7];
  const float* reg_wo = (const float*)d_in[8];
  const float* reg_bo = (const float*)d_in[9];
  const float* cls_w  = (const float*)d_in[10];
  const float* cls_b  = (const float*)d_in[11];
  const float* cls_wo = (const float*)d_in[12];
  const float* cls_bo = (const float*)d_in[13];
  __bf16* ws = (__bf16*)d_ws;

  Desc dmid, dout_d;
  for (int i = 0; i < 6; ++i) {
    LevelD L;
    L.H = kH[i]; L.W = kW[i]; L.logW = kLogW[i]; L.logHW = kLogHW[i];
    L.HW = kH[i] * kW[i]; L.P = 8 * L.HW;
    L.act_off = kActOff[i]; L.aoff = kAoff[i]; L.ntn = kNtn[i];
    L.pos_start = kPosSt[i];
    L.blk_start = kBlkMid[i];
    dmid.lv[i] = L;
    L.blk_start = kBlkOut[i];
    dout_d.lv[i] = L;
  }

  // zero both activation buffers (halos must be zero)
  hipMemsetAsync((char*)d_ws + (size_t)ACT0_OFF * 2, 0,
                 (size_t)ACT_ELEMS * 2 * 2, stream);

  prep_k<<<256, 256, 0, stream>>>(reg_w,  ws + WREG_OFF,  1024 * 2304);
  prep_k<<<256, 256, 0, stream>>>(cls_w,  ws + WCLS_OFF,  1024 * 2304);
  prep_k<<<64,  256, 0, stream>>>(reg_wo, ws + WREGO_OFF, 24 * 2304);
  prep_k<<<64,  256, 0, stream>>>(cls_wo, ws + WCLSO_OFF, 54 * 2304);

  for (int head = 0; head < 2; ++head) {
    convert_k<<<5460, 256, 0, stream>>>(fp, ws + ACT0_OFF, dmid);
    const __bf16* wT = ws + (head ? WCLS_OFF : WREG_OFF);
    const float*  bb = head ? cls_b : reg_b;
    conv_mid_k<<<1366, 256, 0, stream>>>(ws + ACT0_OFF, ws + ACT1_OFF, wT + 0 * 589824, bb + 0,   dmid);
    conv_mid_k<<<1366, 256, 0, stream>>>(ws + ACT1_OFF, ws + ACT0_OFF, wT + 1 * 589824, bb + 256, dmid);
    conv_mid_k<<<1366, 256, 0, stream>>>(ws + ACT0_OFF, ws + ACT1_OFF, wT + 2 * 589824, bb + 512, dmid);
    conv_mid_k<<<1366, 256, 0, stream>>>(ws + ACT1_OFF, ws + ACT0_OFF, wT + 3 * 589824, bb + 768, dmid);
    conv_out_k<<<683, 256, 0, stream>>>(ws + ACT0_OFF,
        ws + (head ? WCLSO_OFF : WREGO_OFF), head ? cls_bo : reg_bo,
        (float*)d_out, dout_d, head ? 54 : 24, head);
  }
}

// Round 4
// 1501.087 us; speedup vs baseline: 1.0665x; 1.0665x over previous
//
#include <hip/hip_runtime.h>
#include <hip/hip_bf16.h>

// RetinaNet head on MI355X. R4: 256co x 128pos block tile, 4 waves of
// 128x64 (mfma_f32_32x32x16_bf16), ring-3 LDS, counted vmcnt, 1 barrier/iter.
// LDS traffic per FLOP cut ~25% vs R3 (the measured LDS-BW wall).

typedef float  f32x4  __attribute__((ext_vector_type(4)));
typedef float  f32x16 __attribute__((ext_vector_type(16)));
typedef int    i32x4  __attribute__((ext_vector_type(4)));
typedef __bf16 bfrag  __attribute__((ext_vector_type(8)));
typedef __bf16 bf4    __attribute__((ext_vector_type(4)));

struct LevelD {
  int H, W, logW, logHW, P, HW, act_off, aoff, blk_start, pos_start;
};
struct Desc  { LevelD lv[6]; };
struct FPtrs { const float* f[6]; };

#define ACT_ELEMS  24735744
#define WREG_OFF   0
#define WCLS_OFF   2359296
#define WREGO_OFF  4718592
#define WCLSO_OFF  4773888
#define ACT0_OFF   4898304
#define ACT1_OFF   29634048
#define WS_ELEMS   54369792ull
#define TOTAL_ANCH 65520
#define CLS_BASE   2096640

__device__ __forceinline__ void glds16(const __bf16* g, __bf16* l) {
  __builtin_amdgcn_global_load_lds(
      (const __attribute__((address_space(1))) void*)g,
      (__attribute__((address_space(3))) void*)l, 16, 0, 0);
}

// ---- weight prep: [CO][256ci][3][3] f32 -> [CO][t=9][256ci] bf16 ----
__global__ __launch_bounds__(256) void prep_k(const float* __restrict__ w,
                                              __bf16* __restrict__ o, int total)
{
  for (int i = blockIdx.x * 256 + threadIdx.x; i < total; i += gridDim.x * 256) {
    int co = i / 2304;
    int r  = i - co * 2304;
    int t  = r >> 8;
    int ci = r & 255;
    o[i] = (__bf16)w[((co << 8) + ci) * 9 + t];
  }
}

// ---- NCHW f32 feat -> padded NHWC bf16 (interior only; halos pre-zeroed) ----
__global__ __launch_bounds__(256) void convert_k(FPtrs fp, __bf16* __restrict__ act, Desc d)
{
  __shared__ __bf16 T[16 * 264];
  int b  = blockIdx.x;
  int p0 = b << 4;
  int li = 0;
  #pragma unroll
  for (int i = 1; i < 6; ++i) li = (p0 >= d.lv[i].pos_start) ? i : li;
  LevelD L = d.lv[li];
  int lp  = b * 16 - L.pos_start;
  int tid = threadIdx.x;
  int pl = tid & 15;
  int p  = lp + pl;
  int n  = p >> L.logHW;
  int y  = (p >> L.logW) & (L.H - 1);
  int x  = p & (L.W - 1);
  const float* src = fp.f[li];
  size_t base = (size_t)n * ((size_t)L.HW << 8) + (size_t)y * L.W + x;
  int c0 = tid >> 4;
  #pragma unroll
  for (int it = 0; it < 16; ++it) {
    int c = c0 + (it << 4);
    T[pl * 264 + c] = (__bf16)src[base + (size_t)c * L.HW];
  }
  __syncthreads();
  int p2 = tid >> 4;
  int cc = (tid & 15) << 4;
  int pg = lp + p2;
  int n2 = pg >> L.logHW;
  int y2 = (pg >> L.logW) & (L.H - 1);
  int x2 = pg & (L.W - 1);
  __bf16* dst = act + L.act_off +
      ((size_t)((n2 * (L.H + 2) + y2 + 1) * (L.W + 2) + x2 + 1) << 8) + cc;
  i32x4 v0 = *(const i32x4*)&T[p2 * 264 + cc];
  i32x4 v1 = *(const i32x4*)&T[p2 * 264 + cc + 8];
  *(i32x4*)dst       = v0;
  *(i32x4*)(dst + 8) = v1;
}

// ---- mid conv: 256->256, +bias, ReLU ----
// BM=256 co (all), BN=128 pos. 4 waves (2co x 2pos), wave tile 128x64.
// mfma_f32_32x32x16_bf16, acc[4ct][2pt] of f32x16. Ring-3 LDS, vmcnt(6).
__global__ __launch_bounds__(256, 2)
void conv_mid_k(const __bf16* __restrict__ inb, __bf16* __restrict__ outb,
                const __bf16* __restrict__ wT, const float* __restrict__ bias,
                Desc d)
{
  __shared__ __bf16 Asm[3 * 8192];   // 3 bufs x [256 rows][32 k] (64B rows)
  __shared__ __bf16 Bsm[3 * 4096];   // 3 bufs x [128 rows][32 k]
  int b  = blockIdx.x;
  int li = 0;
  #pragma unroll
  for (int i = 1; i < 6; ++i) li = (b >= d.lv[i].blk_start) ? i : li;
  LevelD L = d.lv[li];
  int p0 = (b - L.blk_start) << 7;
  int tid  = threadIdx.x;
  int lane = tid & 63;
  int wv   = tid >> 6;
  int wm = wv >> 1, wn = wv & 1;
  int wl = lane & 31, lh = lane >> 5;
  int Wp = L.W + 2;

  // ---- staging: thread -> (row = tid>>2, slot = tid&3), source-side swizzle
  int srow = tid >> 2;
  int slot = tid & 3;
  int sw   = slot ^ ((srow >> 1) & 3);
  const __bf16* gA[4];
  #pragma unroll
  for (int i = 0; i < 4; ++i)
    gA[i] = wT + (i * 64 + srow) * 2304 + (sw << 3);
  const __bf16* gB[2];
  #pragma unroll
  for (int j = 0; j < 2; ++j) {
    int p  = p0 + j * 64 + srow;
    int pc = (p < L.P) ? p : 0;
    int n = pc >> L.logHW, y = (pc >> L.logW) & (L.H - 1), x = pc & (L.W - 1);
    gB[j] = inb + L.act_off + (((n * (L.H + 2) + y) * Wp + x) << 8) + (sw << 3);
  }
  int stW = wv << 9;   // wave-uniform LDS dest base (elems): wv*512

  // ---- fragment read byte-offsets (swizzled), per kk half ----
  int fsw = (wl >> 1) & 3;
  int aBase[2], bBase[2];
  #pragma unroll
  for (int kk = 0; kk < 2; ++kk) {
    int phys = ((kk << 1) | lh) ^ fsw;
    aBase[kk] = (((wm << 7) + wl) << 6) + (phys << 4);
    bBase[kk] = (((wn << 6) + wl) << 6) + (phys << 4);
  }

  auto stage = [&](int k, int bufAe, int bufBe) {
    int t  = k >> 3;
    int ky = (t >= 6) ? 2 : (t >= 3 ? 1 : 0);
    int kx = t - ky * 3;
    int offA = k << 5;                               // t*256 + c0 == k*32
    int offB = ((ky * Wp + kx) << 8) + ((k & 7) << 5);
    #pragma unroll
    for (int i = 0; i < 4; ++i)
      glds16(gA[i] + offA, Asm + bufAe + (i << 11) + stW);
    #pragma unroll
    for (int j = 0; j < 2; ++j)
      glds16(gB[j] + offB, Bsm + bufBe + (j << 11) + stW);
  };

  f32x16 acc[4][2] = {};

  auto compute = [&](int bufAe, int bufBe) {
    const char* Ap = (const char*)(Asm + bufAe);
    const char* Bp = (const char*)(Bsm + bufBe);
    #pragma unroll
    for (int kk = 0; kk < 2; ++kk) {
      bfrag a[4], bb[2];
      #pragma unroll
      for (int ct = 0; ct < 4; ++ct)
        a[ct] = *(const bfrag*)(Ap + aBase[kk] + (ct << 11));
      #pragma unroll
      for (int pt = 0; pt < 2; ++pt)
        bb[pt] = *(const bfrag*)(Bp + bBase[kk] + (pt << 11));
      __builtin_amdgcn_s_setprio(1);
      #pragma unroll
      for (int ct = 0; ct < 4; ++ct)
        #pragma unroll
        for (int pt = 0; pt < 2; ++pt)
          acc[ct][pt] = __builtin_amdgcn_mfma_f32_32x32x16_bf16(
              a[ct], bb[pt], acc[ct][pt], 0, 0, 0);
      __builtin_amdgcn_s_setprio(0);
    }
  };

  stage(0, 0, 0);
  stage(1, 8192, 4096);
  int sA = 16384, sB = 8192;   // stage(k+2) target
  int cA = 0,     cB = 0;      // compute(k) source
  #pragma unroll 1
  for (int k = 0; k < 70; ++k) {
    asm volatile("s_waitcnt vmcnt(6)" ::: "memory");   // stage(k) landed
    __builtin_amdgcn_s_barrier();
    __builtin_amdgcn_sched_barrier(0);
    stage(k + 2, sA, sB);
    compute(cA, cB);
    sA = cA; sB = cB;
    cA = (cA == 16384) ? 0 : cA + 8192;
    cB = (cB == 8192)  ? 0 : cB + 4096;
  }
  asm volatile("s_waitcnt vmcnt(6)" ::: "memory");
  __builtin_amdgcn_s_barrier();
  __builtin_amdgcn_sched_barrier(0);
  compute(cA, cB);
  cA = (cA == 16384) ? 0 : cA + 8192;
  cB = (cB == 8192)  ? 0 : cB + 4096;
  asm volatile("s_waitcnt vmcnt(0)" ::: "memory");
  __builtin_amdgcn_s_barrier();
  __builtin_amdgcn_sched_barrier(0);
  compute(cA, cB);

  // epilogue: C layout col=lane&31(pos), row=(reg&3)+8*(reg>>2)+4*lh (co)
  #pragma unroll
  for (int ct = 0; ct < 4; ++ct) {
    int cob = (wm << 7) + (ct << 5) + (lh << 2);
    #pragma unroll
    for (int pt = 0; pt < 2; ++pt) {
      int posb = p0 + (wn << 6) + (pt << 5);
      if (posb >= L.P) continue;
      int pos = posb + wl;
      int n = pos >> L.logHW, y = (pos >> L.logW) & (L.H - 1), x = pos & (L.W - 1);
      __bf16* ob = outb + L.act_off + (((n * (L.H + 2) + y + 1) * Wp + x + 1) << 8);
      f32x16 v = acc[ct][pt];
      #pragma unroll
      for (int g = 0; g < 4; ++g) {
        int co = cob + (g << 3);
        f32x4 bb4 = *(const f32x4*)(bias + co);
        bf4 ov;
        #pragma unroll
        for (int jj = 0; jj < 4; ++jj)
          ov[jj] = (__bf16)fmaxf(v[(g << 2) + jj] + bb4[jj], 0.0f);
        *(bf4*)(ob + co) = ov;
      }
    }
  }
}

// ---- out conv: 256->Cout (24/54), +bias, scatter f32 to d_out ----
__global__ __launch_bounds__(256, 2)
void conv_out_k(const __bf16* __restrict__ inb, const __bf16* __restrict__ wT,
                const float* __restrict__ biasO, float* __restrict__ dout,
                Desc d, int Cout, int isCls)
{
  __shared__ __bf16 Asm[3 * 2048];   // 3 x [64][32]
  __shared__ __bf16 Bsm[3 * 4096];   // 3 x [128][32]
  int b  = blockIdx.x;
  int li = 0;
  #pragma unroll
  for (int i = 1; i < 6; ++i) li = (b >= d.lv[i].blk_start) ? i : li;
  LevelD L = d.lv[li];
  int p0 = (b - L.blk_start) << 7;
  int tid  = threadIdx.x;
  int lane = tid & 63;
  int wv   = tid >> 6;
  int wm = wv >> 1, wn = wv & 1;
  int wl = lane & 31, lh = lane >> 5;
  int Wp = L.W + 2;
  int nct = (Cout + 31) >> 5;

  int srow = tid >> 2;
  int slot = tid & 3;
  int sw   = slot ^ ((srow >> 1) & 3);
  int arow = (srow < Cout) ? srow : (Cout - 1);
  const __bf16* gA0 = wT + arow * 2304 + (sw << 3);
  const __bf16* gB[2];
  #pragma unroll
  for (int j = 0; j < 2; ++j) {
    int p  = p0 + j * 64 + srow;
    int pc = (p < L.P) ? p : 0;
    int n = pc >> L.logHW, y = (pc >> L.logW) & (L.H - 1), x = pc & (L.W - 1);
    gB[j] = inb + L.act_off + (((n * (L.H + 2) + y) * Wp + x) << 8) + (sw << 3);
  }
  int stW = wv << 9;

  int fsw = (wl >> 1) & 3;
  int aBase[2], bBase[2];
  #pragma unroll
  for (int kk = 0; kk < 2; ++kk) {
    int phys = ((kk << 1) | lh) ^ fsw;
    aBase[kk] = (wl << 6) + (phys << 4);
    bBase[kk] = (((wn << 6) + wl) << 6) + (phys << 4);
  }

  auto stage = [&](int k, int bufAe, int bufBe) {
    int t  = k >> 3;
    int ky = (t >= 6) ? 2 : (t >= 3 ? 1 : 0);
    int kx = t - ky * 3;
    int offA = k << 5;
    int offB = ((ky * Wp + kx) << 8) + ((k & 7) << 5);
    glds16(gA0 + offA, Asm + bufAe + stW);
    #pragma unroll
    for (int j = 0; j < 2; ++j)
      glds16(gB[j] + offB, Bsm + bufBe + (j << 11) + stW);
  };

  f32x16 acc[2][2] = {};

  auto compute = [&](int bufAe, int bufBe) {
    if (wm != 0) return;
    const char* Ap = (const char*)(Asm + bufAe);
    const char* Bp = (const char*)(Bsm + bufBe);
    #pragma unroll
    for (int kk = 0; kk < 2; ++kk) {
      bfrag a[2], bb[2];
      #pragma unroll
      for (int ct = 0; ct < 2; ++ct)
        if (ct < nct) a[ct] = *(const bfrag*)(Ap + aBase[kk] + (ct << 11));
      #pragma unroll
      for (int pt = 0; pt < 2; ++pt)
        bb[pt] = *(const bfrag*)(Bp + bBase[kk] + (pt << 11));
      #pragma unroll
      for (int ct = 0; ct < 2; ++ct)
        if (ct < nct)
          #pragma unroll
          for (int pt = 0; pt < 2; ++pt)
            acc[ct][pt] = __builtin_amdgcn_mfma_f32_32x32x16_bf16(
                a[ct], bb[pt], acc[ct][pt], 0, 0, 0);
    }
  };

  stage(0, 0, 0);
  stage(1, 2048, 4096);
  int sA = 4096, sB = 8192;
  int cA = 0,    cB = 0;
  #pragma unroll 1
  for (int k = 0; k < 70; ++k) {
    asm volatile("s_waitcnt vmcnt(3)" ::: "memory");
    __builtin_amdgcn_s_barrier();
    __builtin_amdgcn_sched_barrier(0);
    stage(k + 2, sA, sB);
    compute(cA, cB);
    sA = cA; sB = cB;
    cA = (cA == 4096) ? 0 : cA + 2048;
    cB = (cB == 8192) ? 0 : cB + 4096;
  }
  asm volatile("s_waitcnt vmcnt(3)" ::: "memory");
  __builtin_amdgcn_s_barrier();
  __builtin_amdgcn_sched_barrier(0);
  compute(cA, cB);
  cA = (cA == 4096) ? 0 : cA + 2048;
  cB = (cB == 8192) ? 0 : cB + 4096;
  asm volatile("s_waitcnt vmcnt(0)" ::: "memory");
  __builtin_amdgcn_s_barrier();
  __builtin_amdgcn_sched_barrier(0);
  compute(cA, cB);

  if (wm == 0) {
    #pragma unroll
    for (int ct = 0; ct < 2; ++ct) {
      if (ct < nct) {
        #pragma unroll
        for (int pt = 0; pt < 2; ++pt) {
          int posb = p0 + (wn << 6) + (pt << 5);
          if (posb >= L.P) continue;
          int pos = posb + wl;
          int n = pos >> L.logHW, y = (pos >> L.logW) & (L.H - 1), x = pos & (L.W - 1);
          int sp_off = L.aoff + y * L.W + x;
          f32x16 v = acc[ct][pt];
          #pragma unroll
          for (int g = 0; g < 4; ++g)
            #pragma unroll
            for (int jj = 0; jj < 4; ++jj) {
              int co = (ct << 5) + (lh << 2) + (g << 3) + jj;
              if (co < Cout) {
                float val = v[(g << 2) + jj] + biasO[co];
                int gg  = co / 6;
                int box = co - gg * 6;
                size_t idx;
                if (isCls) idx = (size_t)CLS_BASE + ((size_t)n * 9 + gg) * TOTAL_ANCH
                                 + sp_off + box * L.HW;
                else       idx = ((size_t)n * 4 + gg) * TOTAL_ANCH + sp_off + box * L.HW;
                dout[idx] = val;
              }
            }
        }
      }
    }
  }
}

extern "C" void kernel_launch(void* const* d_in, const int* in_sizes, int n_in,
                              void* d_out, int out_size, void* d_ws, size_t ws_size,
                              hipStream_t stream) {
  if (ws_size < WS_ELEMS * 2) return;  // fail loud: output stays poisoned

  static const int kH[6]      = {32, 16, 8, 4, 2, 1};
  static const int kW[6]      = {256, 128, 64, 32, 16, 8};
  static const int kLogW[6]   = {8, 7, 6, 5, 4, 3};
  static const int kLogHW[6]  = {13, 11, 9, 7, 5, 3};
  static const int kActOff[6] = {0, 17965056, 22757376, 24109056, 24526848, 24674304};
  static const int kAoff[6]   = {0, 49152, 61440, 64512, 65280, 65472};
  static const int kBlk[6]    = {0, 512, 640, 672, 680, 682};
  static const int kPosSt[6]  = {0, 65536, 81920, 86016, 87040, 87296};

  FPtrs fp;
  for (int i = 0; i < 6; ++i) fp.f[i] = (const float*)d_in[i];
  const float* reg_w  = (const float*)d_in[6];
  const float* reg_b  = (const float*)d_in[7];
  const float* reg_wo = (const float*)d_in[8];
  const float* reg_bo = (const float*)d_in[9];
  const float* cls_w  = (const float*)d_in[10];
  const float* cls_b  = (const float*)d_in[11];
  const float* cls_wo = (const float*)d_in[12];
  const float* cls_bo = (const float*)d_in[13];
  __bf16* ws = (__bf16*)d_ws;

  Desc dd;
  for (int i = 0; i < 6; ++i) {
    LevelD L;
    L.H = kH[i]; L.W = kW[i]; L.logW = kLogW[i]; L.logHW = kLogHW[i];
    L.HW = kH[i] * kW[i]; L.P = 8 * L.HW;
    L.act_off = kActOff[i]; L.aoff = kAoff[i];
    L.blk_start = kBlk[i]; L.pos_start = kPosSt[i];
    dd.lv[i] = L;
  }

  // zero both activation buffers (halos must be zero)
  hipMemsetAsync((char*)d_ws + (size_t)ACT0_OFF * 2, 0,
                 (size_t)ACT_ELEMS * 2 * 2, stream);

  prep_k<<<256, 256, 0, stream>>>(reg_w,  ws + WREG_OFF,  1024 * 2304);
  prep_k<<<256, 256, 0, stream>>>(cls_w,  ws + WCLS_OFF,  1024 * 2304);
  prep_k<<<64,  256, 0, stream>>>(reg_wo, ws + WREGO_OFF, 24 * 2304);
  prep_k<<<64,  256, 0, stream>>>(cls_wo, ws + WCLSO_OFF, 54 * 2304);

  for (int head = 0; head < 2; ++head) {
    convert_k<<<5460, 256, 0, stream>>>(fp, ws + ACT0_OFF, dd);
    const __bf16* wT = ws + (head ? WCLS_OFF : WREG_OFF);
    const float*  bb = head ? cls_b : reg_b;
    conv_mid_k<<<683, 256, 0, stream>>>(ws + ACT0_OFF, ws + ACT1_OFF, wT + 0 * 589824, bb + 0,   dd);
    conv_mid_k<<<683, 256, 0, stream>>>(ws + ACT1_OFF, ws + ACT0_OFF, wT + 1 * 589824, bb + 256, dd);
    conv_mid_k<<<683, 256, 0, stream>>>(ws + ACT0_OFF, ws + ACT1_OFF, wT + 2 * 589824, bb + 512, dd);
    conv_mid_k<<<683, 256, 0, stream>>>(ws + ACT1_OFF, ws + ACT0_OFF, wT + 3 * 589824, bb + 768, dd);
    conv_out_k<<<683, 256, 0, stream>>>(ws + ACT0_OFF,
        ws + (head ? WCLSO_OFF : WREGO_OFF), head ? cls_bo : reg_bo,
        (float*)d_out, dd, head ? 54 : 24, head);
  }
}